// Round 6
// baseline (294.827 us; speedup 1.0000x reference)
//
#include <hip/hip_runtime.h>
#include <math.h>

#define NUM_TREES 4096
#define TOTAL_NODES 1048576
#define DCOL 256
#define DPW 64             // float4 units per row (D=256/4)
#define RUN 16             // rows per grid-stride run
#define NWAVES 4096        // waves in main kernel
#define NRUNS (TOTAL_NODES / RUN)    // 65536
#define SWEEPS (NRUNS / NWAVES)      // 16

typedef float f4v __attribute__((ext_vector_type(4)));

#if __has_builtin(__builtin_nontemporal_load)
#define NTLOAD(p) __builtin_nontemporal_load(p)
#else
#define NTLOAD(p) (*(p))
#endif

// monotone float->uint encoding: unsigned max == float max (proven R4)
static __device__ __forceinline__ unsigned enc(float f) {
    unsigned b = __float_as_uint(f);
    return (b & 0x80000000u) ? ~b : (b | 0x80000000u);
}
static __device__ __forceinline__ float dec(unsigned u) {
    return (u & 0x80000000u) ? __uint_as_float(u ^ 0x80000000u)
                             : __uint_as_float(~u);
}
#define ENC_NEG_INF 0x007FFFFFu   // enc(-inf)

static __device__ __forceinline__ f4v vmax4(f4v a, f4v b) {
    f4v r;
    r.x = fmaxf(a.x, b.x);
    r.y = fmaxf(a.y, b.y);
    r.z = fmaxf(a.z, b.z);
    r.w = fmaxf(a.w, b.w);
    return r;
}

static __device__ __forceinline__ void commit(unsigned* __restrict__ out_u,
                                              int t, int lane, f4v acc) {
    unsigned* dst = out_u + (long)t * DCOL + lane * 4;
    atomicMax(dst + 0, enc(acc.x));
    atomicMax(dst + 1, enc(acc.y));
    atomicMax(dst + 2, enc(acc.z));
    atomicMax(dst + 3, enc(acc.w));
}

// ---------------- Kernel 1 (fused): block 0 = prefix sum; blocks 1..1024 init out ----
// tree_sizes dtype auto-detect (int32 in practice) — proven R4/R5.
__global__ void TreeAgg_prep_init(const void* __restrict__ sizes_raw,
                                  int* __restrict__ row_off,
                                  unsigned* __restrict__ out_u) {
    if (blockIdx.x == 0) {
        __shared__ int s_row[256];
        __shared__ int s_is64;
        const int t = threadIdx.x;            // each owns 16 trees
        const int base = t * 16;
        const int* s32 = (const int*)sizes_raw;

        int ls[16];
        int rsum = 0;
        #pragma unroll
        for (int i = 0; i < 16; ++i) { ls[i] = s32[base + i]; rsum += ls[i]; }
        s_row[t] = rsum;
        __syncthreads();
        if (t == 0) {
            long long tot = 0;
            for (int i = 0; i < 256; ++i) tot += (long long)s_row[i];
            s_is64 = (tot != (long long)TOTAL_NODES) ? 1 : 0;
        }
        __syncthreads();
        if (s_is64) {
            const long long* s64 = (const long long*)sizes_raw;
            #pragma unroll
            for (int i = 0; i < 16; ++i) ls[i] = (int)s64[base + i];
            int rs = 0;
            #pragma unroll
            for (int i = 0; i < 16; ++i) rs += ls[i];
            s_row[t] = rs;
            __syncthreads();
        }
        if (t == 0) {
            int ra = 0;
            for (int i = 0; i < 256; ++i) { int r = s_row[i]; s_row[i] = ra; ra += r; }
            row_off[NUM_TREES] = ra;          // == TOTAL_NODES
        }
        __syncthreads();
        int ro = s_row[t];
        #pragma unroll
        for (int i = 0; i < 16; ++i) { row_off[base + i] = ro; ro += ls[i]; }
    } else {
        const int i = (blockIdx.x - 1) * blockDim.x + threadIdx.x;   // 262144 uint4
        ((uint4*)out_u)[i] = make_uint4(ENC_NEG_INF, ENC_NEG_INF, ENC_NEG_INF, ENC_NEG_INF);
    }
}

// ---------------- Kernel 2: grid-stride interleaved segment max ----------------
// Run j covers rows [16j, 16j+16). Wave w handles runs {g*4096 + w}.
// Concurrently-active addresses sweep one compact 64MB window (DRAM locality).
__global__ __launch_bounds__(256, 4)
void TreeAgg_main(const float* __restrict__ emb,
                  const int* __restrict__ row_off,
                  unsigned* __restrict__ out_u) {
    __shared__ int s_off[NUM_TREES + 1];
    const int tid = threadIdx.x;
    #pragma unroll
    for (int i = 0; i < 16; ++i) s_off[tid * 16 + i] = row_off[tid * 16 + i];
    if (tid == 0) s_off[NUM_TREES] = row_off[NUM_TREES];
    __syncthreads();

    const int wid  = (blockIdx.x * 256 + tid) >> 6;   // 0..4095
    const int lane = tid & 63;
    const f4v* __restrict__ src = (const f4v*)emb;    // row r = f4v idx r*64
    const float NEG = -INFINITY;

    for (int g = 0; g < SWEEPS; ++g) {
        const int j = g * NWAVES + wid;
        const int a = j * RUN;
        const int b = a + RUN;

        // largest t with s_off[t] <= a  (LDS, wave-uniform)
        int lo = 0, hi = NUM_TREES;
        while (hi - lo > 1) {
            int mid = (lo + hi) >> 1;
            if (s_off[mid] <= a) lo = mid; else hi = mid;
        }
        int t = lo;

        if (s_off[t + 1] >= b) {
            // fast path (~94%): whole run inside tree t — 16-deep load unroll
            const long ib = (long)a * DPW + lane;
            f4v v[RUN];
            #pragma unroll
            for (int k = 0; k < RUN; ++k) v[k] = NTLOAD(src + ib + (long)k * DPW);
            #pragma unroll
            for (int s = RUN / 2; s > 0; s >>= 1)
                #pragma unroll
                for (int k = 0; k < s; ++k) v[k] = vmax4(v[k], v[k + s]);
            commit(out_u, t, lane, v[0]);
        } else {
            // slow path: split at tree boundaries inside the run
            int aa = a;
            while (aa < b) {
                const int ee = min(b, s_off[t + 1]);
                f4v acc = { NEG, NEG, NEG, NEG };
                long idx = (long)aa * DPW + lane;
                for (int r = aa; r < ee; ++r, idx += DPW)
                    acc = vmax4(acc, NTLOAD(src + idx));
                commit(out_u, t, lane, acc);
                aa = ee;
                if (aa < b) ++t;
            }
        }
    }
}

// ---------------- Kernel 3: decode d_out in place ----------------
__global__ void TreeAgg_decode(unsigned* __restrict__ out_u) {
    const int i = blockIdx.x * blockDim.x + threadIdx.x;   // 262144 uint4
    uint4 v = ((uint4*)out_u)[i];
    float4 f;
    f.x = dec(v.x); f.y = dec(v.y); f.z = dec(v.z); f.w = dec(v.w);
    ((float4*)out_u)[i] = f;
}

extern "C" void kernel_launch(void* const* d_in, const int* in_sizes, int n_in,
                              void* d_out, int out_size, void* d_ws, size_t ws_size,
                              hipStream_t stream) {
    const float* emb   = (const float*)d_in[0];
    const void*  sizes = d_in[1];                 // int32 or int64, auto-detected
    unsigned*    out_u = (unsigned*)d_out;

    int* row_off = (int*)d_ws;                    // 4097 ints

    TreeAgg_prep_init<<<1025, 256, 0, stream>>>(sizes, row_off, out_u);

    // main: 4096 waves (1024 blocks x 4 waves), 16 sweeps of a 64MB window
    TreeAgg_main<<<NWAVES * 64 / 256, 256, 0, stream>>>(emb, row_off, out_u);

    TreeAgg_decode<<<1024, 256, 0, stream>>>(out_u);
}

// Round 7
// 243.145 us; speedup vs baseline: 1.2126x; 1.2126x over previous
//
#include <hip/hip_runtime.h>
#include <math.h>

#define NUM_TREES 4096
#define TOTAL_NODES 1048576
#define DCOL 256
#define DPW 64             // float4 units per row (D=256/4)
#define SLICE 128          // rows per wave: 8192 waves * 128 = TOTAL_NODES
#define NWAVES 8192

typedef float f4v __attribute__((ext_vector_type(4)));

static __device__ __forceinline__ f4v vmax4(f4v a, f4v b) {
    f4v r;
    r.x = fmaxf(a.x, b.x);
    r.y = fmaxf(a.y, b.y);
    r.z = fmaxf(a.z, b.z);
    r.w = fmaxf(a.w, b.w);
    return r;
}

// float atomic max via CAS loop (proven R5)
static __device__ __forceinline__ void atomicFmax(float* addr, float val) {
    unsigned* u = (unsigned*)addr;
    unsigned old = *u;
    while (__uint_as_float(old) < val) {
        unsigned assumed = old;
        old = atomicCAS(u, assumed, __float_as_uint(val));
        if (old == assumed) break;
    }
}

// stream rows [lo,hi), split at tree boundaries, commit each segment's max
static __device__ __forceinline__ void process_range(const f4v* __restrict__ src,
                                                     const int* __restrict__ row_off,
                                                     float* __restrict__ out,
                                                     int lane, int lo, int hi) {
    if (lo >= hi) return;
    // largest t with row_off[t] <= lo (wave-uniform)
    int l = 0, h = NUM_TREES;
    while (h - l > 1) {
        int mid = (l + h) >> 1;
        if (row_off[mid] <= lo) l = mid; else h = mid;
    }
    int t = l;
    const float NEG = -INFINITY;
    long idx = (long)lo * DPW + lane;
    while (lo < hi) {
        int e = min(hi, row_off[t + 1]);
        if (e <= lo) break;                   // insurance vs corrupt offsets
        f4v acc = { NEG, NEG, NEG, NEG };
        int r = lo;
        for (; r + 4 <= e; r += 4, idx += 4 * DPW) {
            f4v x = src[idx];
            f4v y = src[idx + DPW];
            f4v z = src[idx + 2 * DPW];
            f4v w = src[idx + 3 * DPW];
            acc = vmax4(acc, vmax4(vmax4(x, y), vmax4(z, w)));
        }
        for (; r < e; ++r, idx += DPW) acc = vmax4(acc, src[idx]);
        float* dst = out + (long)t * DCOL + lane * 4;
        atomicFmax(dst + 0, acc.x);
        atomicFmax(dst + 1, acc.y);
        atomicFmax(dst + 2, acc.z);
        atomicFmax(dst + 3, acc.w);
        lo = e;
        ++t;
    }
}

// ---------------- Kernel 1 (fused): block 0 = prefix sum; blocks 1..1024 init out ----
// tree_sizes dtype auto-detect (int32 in practice) — proven R4/R5.
__global__ void TreeAgg_prep_init(const void* __restrict__ sizes_raw,
                                  int* __restrict__ row_off,
                                  float* __restrict__ out) {
    if (blockIdx.x == 0) {
        __shared__ int s_row[256];
        __shared__ int s_is64;
        const int t = threadIdx.x;            // each owns 16 trees
        const int base = t * 16;
        const int* s32 = (const int*)sizes_raw;

        int ls[16];
        int rsum = 0;
        #pragma unroll
        for (int i = 0; i < 16; ++i) { ls[i] = s32[base + i]; rsum += ls[i]; }
        s_row[t] = rsum;
        __syncthreads();
        if (t == 0) {
            long long tot = 0;
            for (int i = 0; i < 256; ++i) tot += (long long)s_row[i];
            s_is64 = (tot != (long long)TOTAL_NODES) ? 1 : 0;
        }
        __syncthreads();
        if (s_is64) {
            const long long* s64 = (const long long*)sizes_raw;
            #pragma unroll
            for (int i = 0; i < 16; ++i) ls[i] = (int)s64[base + i];
            int rs = 0;
            #pragma unroll
            for (int i = 0; i < 16; ++i) rs += ls[i];
            s_row[t] = rs;
            __syncthreads();
        }
        if (t == 0) {
            int ra = 0;
            for (int i = 0; i < 256; ++i) { int r = s_row[i]; s_row[i] = ra; ra += r; }
            row_off[NUM_TREES] = ra;          // == TOTAL_NODES
        }
        __syncthreads();
        int ro = s_row[t];
        #pragma unroll
        for (int i = 0; i < 16; ++i) { row_off[base + i] = ro; ro += ls[i]; }
    } else {
        const int i = (blockIdx.x - 1) * blockDim.x + threadIdx.x;   // 262144 float4
        const float NEG = -INFINITY;
        ((float4*)out)[i] = make_float4(NEG, NEG, NEG, NEG);
    }
}

// ---------------- Kernel 2: balanced streams with per-wave phase rotation ----------------
// Wave w owns rows [w*128, w*128+128) but starts at rotated offset (53*w)%128 and
// wraps: de-phases the 8192 concurrent 128KB-strided streams across HBM channels.
__global__ __launch_bounds__(256, 8)
void TreeAgg_main(const float* __restrict__ emb,
                  const int* __restrict__ row_off,
                  float* __restrict__ out) {
    const int wid  = (blockIdx.x * 256 + threadIdx.x) >> 6;   // 0..8191
    const int lane = threadIdx.x & 63;

    const int a = wid * SLICE;
    const int b = a + SLICE;
    const int rot = (wid * 53) & (SLICE - 1);
    const int m = a + rot;

    const f4v* __restrict__ src = (const f4v*)emb;   // row r = f4v idx r*64

    process_range(src, row_off, out, lane, m, b);    // [a+rot, b)
    process_range(src, row_off, out, lane, a, m);    // [a, a+rot)
}

extern "C" void kernel_launch(void* const* d_in, const int* in_sizes, int n_in,
                              void* d_out, int out_size, void* d_ws, size_t ws_size,
                              hipStream_t stream) {
    const float* emb   = (const float*)d_in[0];
    const void*  sizes = d_in[1];                 // int32 or int64, auto-detected
    float*       out   = (float*)d_out;

    int* row_off = (int*)d_ws;                    // 4097 ints

    TreeAgg_prep_init<<<1025, 256, 0, stream>>>(sizes, row_off, out);

    // main: 8192 waves, 4 waves/block -> 2048 blocks
    TreeAgg_main<<<NWAVES * 64 / 256, 256, 0, stream>>>(emb, row_off, out);
}